// Round 1
// baseline (327.566 us; speedup 1.0000x reference)
//
#include <hip/hip_runtime.h>
#include <utility>

// RNN: h_{t+1} = relu(x_t * W_ih^T + b_ih + b_hh + h_t @ W_hh^T), out = h_T @ fc_w^T + fc_b
// B=4096, T=1000, H=20.
//
// Decomposition: 4 lanes per batch element. Lane `sub` (0..3) owns outputs
// j = sub*5 .. sub*5+4 and keeps its 5x20 slice of W_hh in VGPRs (~100 regs).
// The 20 h-values are shared across the quad with DPP quad_perm broadcasts
// (full-rate VALU, no LDS pipe). 16384 threads = 256 waves on 1024 SIMDs ->
// each wave issues at full rate; wall time ~ 1000 * per-step-insts * 2cyc.

#define HID 20
#define TT  1000

template <int Q>
__device__ __forceinline__ float quad_bcast(float v) {
    // quad_perm ctrl: all four 2-bit selectors = Q  -> broadcast lane Q of each quad
    int r = __builtin_amdgcn_update_dpp(0, __float_as_int(v),
                                        (Q * 0x55), 0xF, 0xF, true);
    return __int_as_float(r);
}

template <int K>
__device__ __forceinline__ void fma_k(float (&acc)[5], const float (&w)[100],
                                      const float (&h)[5]) {
    constexpr int q = K / 5;
    constexpr int r = K - q * 5;
    float bk = quad_bcast<q>(h[r]);
#pragma unroll
    for (int j = 0; j < 5; ++j)
        acc[j] = __builtin_fmaf(bk, w[j * HID + K], acc[j]);
}

template <int... Ks>
__device__ __forceinline__ void all_k(float (&acc)[5], const float (&w)[100],
                                      const float (&h)[5],
                                      std::integer_sequence<int, Ks...>) {
    (fma_k<Ks>(acc, w, h), ...);
}

__global__ void __launch_bounds__(256)
rnn_quad_kernel(const float* __restrict__ x,
                const float* __restrict__ W_ih,
                const float* __restrict__ W_hh,
                const float* __restrict__ b_ih,
                const float* __restrict__ b_hh,
                const float* __restrict__ fc_w,
                const float* __restrict__ fc_b,
                float* __restrict__ out) {
    const int tid = blockIdx.x * blockDim.x + threadIdx.x;
    const int b   = tid >> 2;   // batch element, 0..4095
    const int sub = tid & 3;    // lane-in-quad, owns rows sub*5 .. sub*5+4

    // --- load per-lane weight slice into registers (amortized over 1000 steps)
    float w[100];
#pragma unroll
    for (int j = 0; j < 5; ++j)
#pragma unroll
        for (int k = 0; k < HID; ++k)
            w[j * HID + k] = W_hh[(sub * 5 + j) * HID + k];

    float wih[5], bias[5];
#pragma unroll
    for (int j = 0; j < 5; ++j) {
        const int row = sub * 5 + j;
        wih[j]  = W_ih[row];
        bias[j] = b_ih[row] + b_hh[row];
    }

    float h[5] = {0.f, 0.f, 0.f, 0.f, 0.f};

    const float* __restrict__ xb = x + (size_t)b * TT;

    for (int t4 = 0; t4 < TT; t4 += 4) {
        const float4 xq = *(const float4*)(xb + t4);  // row stride 4000B, 16B aligned
#pragma unroll
        for (int c = 0; c < 4; ++c) {
            const float xt = (&xq.x)[c];
            float acc[5];
#pragma unroll
            for (int j = 0; j < 5; ++j)
                acc[j] = __builtin_fmaf(xt, wih[j], bias[j]);

            all_k(acc, w, h, std::make_integer_sequence<int, HID>{});

#pragma unroll
            for (int j = 0; j < 5; ++j)
                h[j] = fmaxf(acc[j], 0.f);
        }
    }

    // --- head: out[b] = sum_j h_T[j] * fc_w[j] + fc_b
    float fcw[5];
#pragma unroll
    for (int j = 0; j < 5; ++j)
        fcw[j] = fc_w[sub * 5 + j];

    float dot = 0.f;
#pragma unroll
    for (int j = 0; j < 5; ++j)
        dot = __builtin_fmaf(h[j], fcw[j], dot);

    // quad reduction (xor by 1 and 2 stays inside the quad)
    dot += __shfl_xor(dot, 1, 4);
    dot += __shfl_xor(dot, 2, 4);

    if (sub == 0)
        out[b] = dot + fc_b[0];
}

extern "C" void kernel_launch(void* const* d_in, const int* in_sizes, int n_in,
                              void* d_out, int out_size, void* d_ws, size_t ws_size,
                              hipStream_t stream) {
    const float* x    = (const float*)d_in[0];
    const float* W_ih = (const float*)d_in[1];
    const float* W_hh = (const float*)d_in[2];
    const float* b_ih = (const float*)d_in[3];
    const float* b_hh = (const float*)d_in[4];
    const float* fc_w = (const float*)d_in[5];
    const float* fc_b = (const float*)d_in[6];
    float* out = (float*)d_out;

    // 4096 batches * 4 lanes = 16384 threads
    const int block = 256;
    const int grid  = (4096 * 4) / block;  // 64 blocks
    rnn_quad_kernel<<<grid, block, 0, stream>>>(x, W_ih, W_hh, b_ih, b_hh,
                                                fc_w, fc_b, out);
}

// Round 2
// 326.227 us; speedup vs baseline: 1.0041x; 1.0041x over previous
//
#include <hip/hip_runtime.h>
#include <utility>

// RNN: h_{t+1} = relu(x_t * W_ih^T + b_ih + b_hh + h_t @ W_hh^T), out = h_T @ fc_w^T + fc_b
// B=4096, T=1000, H=20.
//
// Decomposition: 4 lanes per batch element. Lane `sub` (0..3) owns outputs
// j = sub*5 .. sub*5+4 and keeps its 5x20 slice of W_hh in VGPRs (~100 regs).
// The 20 h-values are shared across the quad with DPP quad_perm broadcasts.
//
// R1 lesson: __launch_bounds__(256) let the allocator cap at 80 VGPRs ->
// w[100] spilled to scratch -> 8 GB of HBM reload traffic (FETCH_SIZE) and
// 275 us. Fix: __launch_bounds__(64, 1) = 1 wave/EU minimum -> up to 512
// VGPRs, array stays in registers. 64-thread blocks spread the 256 waves
// over all 256 CUs.

#define HID 20
#define TT  1000

template <int Q>
__device__ __forceinline__ float quad_bcast(float v) {
    // quad_perm ctrl: all four 2-bit selectors = Q -> broadcast lane Q of each quad
    int r = __builtin_amdgcn_update_dpp(0, __float_as_int(v),
                                        (Q * 0x55), 0xF, 0xF, true);
    return __int_as_float(r);
}

template <int K>
__device__ __forceinline__ void fma_k(float (&acc)[5], const float (&w)[100],
                                      const float (&h)[5]) {
    constexpr int q = K / 5;
    constexpr int r = K - q * 5;
    float bk = quad_bcast<q>(h[r]);
#pragma unroll
    for (int j = 0; j < 5; ++j)
        acc[j] = __builtin_fmaf(bk, w[j * HID + K], acc[j]);
}

template <int... Ks>
__device__ __forceinline__ void all_k(float (&acc)[5], const float (&w)[100],
                                      const float (&h)[5],
                                      std::integer_sequence<int, Ks...>) {
    (fma_k<Ks>(acc, w, h), ...);
}

__global__ void __launch_bounds__(64, 1)
rnn_quad_kernel(const float* __restrict__ x,
                const float* __restrict__ W_ih,
                const float* __restrict__ W_hh,
                const float* __restrict__ b_ih,
                const float* __restrict__ b_hh,
                const float* __restrict__ fc_w,
                const float* __restrict__ fc_b,
                float* __restrict__ out) {
    const int tid = blockIdx.x * blockDim.x + threadIdx.x;
    const int b   = tid >> 2;   // batch element, 0..4095
    const int sub = tid & 3;    // lane-in-quad, owns rows sub*5 .. sub*5+4

    // --- per-lane weight slice in registers (amortized over 1000 steps)
    float w[100];
#pragma unroll
    for (int j = 0; j < 5; ++j)
#pragma unroll
        for (int k = 0; k < HID; ++k)
            w[j * HID + k] = W_hh[(sub * 5 + j) * HID + k];

    float wih[5], bias[5];
#pragma unroll
    for (int j = 0; j < 5; ++j) {
        const int row = sub * 5 + j;
        wih[j]  = W_ih[row];
        bias[j] = b_ih[row] + b_hh[row];
    }

    float h[5] = {0.f, 0.f, 0.f, 0.f, 0.f};

    const float* __restrict__ xb = x + (size_t)b * TT;

    for (int t4 = 0; t4 < TT; t4 += 4) {
        const float4 xq = *(const float4*)(xb + t4);  // row stride 4000B, 16B aligned
#pragma unroll
        for (int c = 0; c < 4; ++c) {
            const float xt = (&xq.x)[c];
            float acc[5];
#pragma unroll
            for (int j = 0; j < 5; ++j)
                acc[j] = __builtin_fmaf(xt, wih[j], bias[j]);

            all_k(acc, w, h, std::make_integer_sequence<int, HID>{});

#pragma unroll
            for (int j = 0; j < 5; ++j)
                h[j] = fmaxf(acc[j], 0.f);
        }
    }

    // --- head: out[b] = sum_j h_T[j] * fc_w[j] + fc_b
    float fcw[5];
#pragma unroll
    for (int j = 0; j < 5; ++j)
        fcw[j] = fc_w[sub * 5 + j];

    float dot = 0.f;
#pragma unroll
    for (int j = 0; j < 5; ++j)
        dot = __builtin_fmaf(h[j], fcw[j], dot);

    // quad reduction (xor by 1 and 2 stays inside the quad)
    dot += __shfl_xor(dot, 1, 4);
    dot += __shfl_xor(dot, 2, 4);

    if (sub == 0)
        out[b] = dot + fc_b[0];
}

extern "C" void kernel_launch(void* const* d_in, const int* in_sizes, int n_in,
                              void* d_out, int out_size, void* d_ws, size_t ws_size,
                              hipStream_t stream) {
    const float* x    = (const float*)d_in[0];
    const float* W_ih = (const float*)d_in[1];
    const float* W_hh = (const float*)d_in[2];
    const float* b_ih = (const float*)d_in[3];
    const float* b_hh = (const float*)d_in[4];
    const float* fc_w = (const float*)d_in[5];
    const float* fc_b = (const float*)d_in[6];
    float* out = (float*)d_out;

    // 4096 batches * 4 lanes = 16384 threads; 64-thread blocks -> 256 blocks,
    // one wave per block, spread across all 256 CUs.
    const int block = 64;
    const int grid  = (4096 * 4) / block;  // 256 blocks
    rnn_quad_kernel<<<grid, block, 0, stream>>>(x, W_ih, W_hh, b_ih, b_hh,
                                                fc_w, fc_b, out);
}